// Round 6
// baseline (67.169 us; speedup 1.0000x reference)
//
#include <hip/hip_runtime.h>
#include <hip/hip_bf16.h>
#include <math.h>

// Sizes fixed by the reference
#define NN 512
#define NQ 448
#define ND 64          // num_denoising
#define NC 91
#define ED 256
#define NH 8

struct FreqArg { float fr[32]; };

// All scratch in device globals — no dependence on ws_size.
__device__ int   g_perm[NN];
__device__ float g_WK[2048];      // 32 k * 4 f * 8 h * {sin,cos}
__device__ float g_w2a[NH * ED];
__device__ float g_c0[NH];
__device__ float g_u[NH * ED];    // u[h,c] = sum_d w2a[h,d] * pre_W[d,c]
__device__ float g_b2a[NH];       // sum_d w2a[h,d] * pre_b[d]
__device__ float g_afull[NN * NH];

// ---------------- K1: blocks 0..7 = fold head h=bid (coalesced over columns);
//                     block 8 = rank/argsort (+c0 on threads 448-455)
__global__ __launch_bounds__(512) void precomp_fold(const float* __restrict__ logits,
                                                    const float* __restrict__ attn_W,
                                                    const float* __restrict__ attn_b,
                                                    const float* __restrict__ post_W,
                                                    const float* __restrict__ post_b,
                                                    float* __restrict__ out2) {
    int bid = blockIdx.x;
    int t = threadIdx.x;
    if (bid < NH) {
        // head h = bid; thread t = output column d' in [0,512)
        __shared__ float sAW[ED];
        int h = bid;
        if (t < ED) sAW[t] = attn_W[h * ED + t];
        __syncthreads();
        float m = 0.f;
        // post_W[c*512 + t]: consecutive t -> coalesced 256B/wave per iteration
        for (int c = 0; c < ED; ++c) m = fmaf(sAW[c], post_W[(size_t)c * 512 + t], m);
        int part = t >> 8;          // 0: pos-weight (W1), 1: rank-weight (W2)
        int d = t & 255;
        if (part == 0) {
            // d = f*64 + 2k + r  ->  WK[(k*4+f)*16 + h*2 + r]
            int f = d >> 6, rem = d & 63, k = rem >> 1, r = rem & 1;
            g_WK[(k * 4 + f) * 16 + h * 2 + r] = m;
        } else {
            g_w2a[h * ED + d] = m;
        }
    } else {
        // rank block: scores -> stable descending argsort -> perm + rank_indices (f32)
        __shared__ float sc[NQ];
        if (t < NQ) {
            const float* row = logits + (size_t)(ND + t) * NC;
            float m = row[0];
            for (int c = 1; c < NC; ++c) m = fmaxf(m, row[c]);
            sc[t] = 1.0f / (1.0f + expf(-m));   // sigmoid(max) == max(sigmoid), monotone
        } else if (t < NQ + NH) {
            // c0[h] = attn_b[h] + attn_W[h,:] @ post_b  (8 spare threads)
            int h = t - NQ;
            float cc = attn_b[h];
            for (int c = 0; c < ED; ++c) cc = fmaf(attn_W[h * ED + c], post_b[c], cc);
            g_c0[h] = cc;
        }
        __syncthreads();
        if (t < NQ) {
            float s = sc[t];
            int rank = 0;
            for (int j = 0; j < NQ; ++j) {
                float sj = sc[j];
                rank += ((sj > s) || (sj == s && j < t)) ? 1 : 0;   // stable descending
            }
            g_perm[ND + rank] = ND + t;
            out2[ND + rank] = (float)(ND + t);
        }
        if (t < ND) {
            g_perm[t] = t;
            out2[t] = (float)t;
            for (int h = 0; h < NH; ++h) g_afull[t * NH + h] = 0.f;
        }
    }
}

// ---------------- K2: u[h,:] = w2a[h,:] @ pre_W  (coalesced over c), b2a[h] via block reduce
__global__ __launch_bounds__(256) void precomp_u(const float* __restrict__ pre_W,
                                                 const float* __restrict__ pre_b) {
    int h = blockIdx.x, c = threadIdx.x;
    __shared__ float sW[ED];
    __shared__ float red[ED];
    sW[c] = g_w2a[h * ED + c];
    __syncthreads();
    float acc = 0.f;
    for (int d = 0; d < ED; ++d) acc = fmaf(sW[d], pre_W[(size_t)d * ED + c], acc);
    g_u[h * ED + c] = acc;
    red[c] = sW[c] * pre_b[c];
    __syncthreads();
    for (int s2 = 128; s2 > 0; s2 >>= 1) {
        if (c < s2) red[c] += red[c + s2];
        __syncthreads();
    }
    if (c == 0) g_b2a[h] = red[0];
}

// ---------------- K3: afull[64+q,h] = b2a[h] + remb[q,:] @ u[h,:]   (32 q x 8 h per block)
__global__ __launch_bounds__(256) void precomp_afull(const float* __restrict__ rank_emb) {
    __shared__ float sU[NH][ED + 1];
    __shared__ float sR[32][ED + 1];
    int t = threadIdx.x;
    int q0 = blockIdx.x * 32;
    for (int v = t; v < NH * ED; v += 256) sU[v >> 8][v & 255] = g_u[v];
    for (int v = t; v < 32 * ED; v += 256)
        sR[v >> 8][v & 255] = rank_emb[(size_t)(q0 + (v >> 8)) * ED + (v & 255)];
    __syncthreads();
    int qloc = t >> 3, h = t & 7;
    float acc = g_b2a[h];
    for (int c = 0; c < ED; ++c) acc = fmaf(sR[qloc][c], sU[h][c], acc);
    g_afull[(size_t)(ND + q0 + qloc) * NH + h] = acc;
}

// ---------------- K4: main per-pair kernel (f32 output), WK staged in LDS
__global__ __launch_bounds__(256) void relation_main(const float* __restrict__ boxes,
                                                     FreqArg fa,
                                                     float* __restrict__ out) {
    __shared__ float sWK[2048];
    int t = threadIdx.x;
    for (int v = t; v < 2048; v += 256) sWK[v] = g_WK[v];
    __syncthreads();

    int idx = blockIdx.x * 256 + t;
    int i = idx >> 9, j = idx & (NN - 1);
    int pi = i, pj = j;
    if (i >= ND && j >= ND) { pi = g_perm[i]; pj = g_perm[j]; }
    float4 b1 = ((const float4*)boxes)[pi];
    float4 b2 = ((const float4*)boxes)[pj];
    const float eps = 1e-5f;
    float feat[4];
    feat[0] = logf(fabsf(b1.x - b2.x) / (b1.z + eps) + 1.0f);
    feat[1] = logf(fabsf(b1.y - b2.y) / (b1.w + eps) + 1.0f);
    feat[2] = logf((b1.z + eps) / (b2.z + eps));
    feat[3] = logf((b1.w + eps) / (b2.w + eps));

    float acc[NH];
#pragma unroll
    for (int h = 0; h < NH; ++h) acc[h] = g_c0[h] + g_afull[i * NH + h] + g_afull[j * NH + h];

#pragma unroll 8
    for (int k = 0; k < 32; ++k) {
        float fr = fa.fr[k];
#pragma unroll
        for (int f = 0; f < 4; ++f) {
            float rev = feat[f] * fr;           // angle in revolutions
            rev = rev - floorf(rev);            // v_fract: safe domain for v_sin/v_cos
            float s = __builtin_amdgcn_sinf(rev);   // sin(2*pi*rev)
            float c = __builtin_amdgcn_cosf(rev);
            const float* w = sWK + ((k * 4 + f) << 4);   // uniform ds_read, broadcast
#pragma unroll
            for (int h = 0; h < NH; ++h) {
                acc[h] = fmaf(s, w[h * 2 + 0], acc[h]);
                acc[h] = fmaf(c, w[h * 2 + 1], acc[h]);
            }
        }
    }
#pragma unroll
    for (int h = 0; h < NH; ++h) {
        float v = acc[h] > 0.f ? acc[h] : 0.f;  // relu
        out[(size_t)h * (NN * NN) + idx] = v;
    }
}

extern "C" void kernel_launch(void* const* d_in, const int* in_sizes, int n_in,
                              void* d_out, int out_size, void* d_ws, size_t ws_size,
                              hipStream_t stream) {
    const float* boxes    = (const float*)d_in[0];
    const float* logits   = (const float*)d_in[1];
    const float* rank_emb = (const float*)d_in[2];
    const float* pre_W    = (const float*)d_in[3];
    const float* pre_b    = (const float*)d_in[4];
    const float* post_W   = (const float*)d_in[5];
    const float* post_b   = (const float*)d_in[6];
    const float* attn_W   = (const float*)d_in[7];
    const float* attn_b   = (const float*)d_in[8];
    float* out = (float*)d_out;

    precomp_fold<<<NH + 1, 512, 0, stream>>>(logits, attn_W, attn_b, post_W, post_b,
                                             out + (size_t)NH * NN * NN);
    precomp_u<<<NH, 256, 0, stream>>>(pre_W, pre_b);
    precomp_afull<<<NQ / 32, 256, 0, stream>>>(rank_emb);

    FreqArg fa;
    for (int k = 0; k < 32; ++k)
        fa.fr[k] = (float)(100.0 / (2.0 * M_PI) / pow(10000.0, (double)k / 32.0));

    relation_main<<<(NN * NN) / 256, 256, 0, stream>>>(boxes, fa, out);
}

// Round 7
// 66.332 us; speedup vs baseline: 1.0126x; 1.0126x over previous
//
#include <hip/hip_runtime.h>
#include <hip/hip_bf16.h>
#include <math.h>

// Sizes fixed by the reference
#define NN 512
#define NQ 448
#define ND 64          // num_denoising
#define NC 91
#define ED 256
#define NH 8

struct FreqArg { float fr[32]; };

// All scratch in device globals — no dependence on ws_size.
__device__ int   g_perm[NN];
__device__ float g_WK[2048];        // 32 k * 4 f * 8 h * {sin,cos}
__device__ float g_c0[NH];
__device__ float g_afull[NN * NH];
__device__ float g_part[64 * 512];  // fold partials: [(h*8+cc)*512 + d']
__device__ float g_pu[64 * ED];     // u partials:    [(h*8+dc)*256 + c]
__device__ float g_pb2a[64];        // b2a partials:  [h*8+dc]

// ---------------- K1: blocks 0..63 = partial fold (h=bid>>3, cc=bid&7, 32 c's);
//                     block 64 = rank/argsort; block 65 = c0 (wave-reduce per head)
__global__ __launch_bounds__(512) void precomp_fold(const float* __restrict__ logits,
                                                    const float* __restrict__ attn_W,
                                                    const float* __restrict__ attn_b,
                                                    const float* __restrict__ post_W,
                                                    const float* __restrict__ post_b,
                                                    float* __restrict__ out2) {
    int bid = blockIdx.x;
    int t = threadIdx.x;
    if (bid < 64) {
        int h = bid >> 3, cc = bid & 7;
        __shared__ float sAW[32];
        if (t < 32) sAW[t] = attn_W[h * ED + cc * 32 + t];
        __syncthreads();
        float m = 0.f;
        const float* pw = post_W + (size_t)(cc * 32) * 512 + t;
#pragma unroll
        for (int ci = 0; ci < 32; ++ci) m = fmaf(sAW[ci], pw[(size_t)ci * 512], m);
        g_part[(size_t)bid * 512 + t] = m;
    } else if (bid == 64) {
        // rank block: scores -> stable descending argsort -> perm + rank_indices (f32)
        __shared__ float sc[NQ];
        if (t < NQ) {
            const float* row = logits + (size_t)(ND + t) * NC;
            float m = row[0];
            for (int c = 1; c < NC; ++c) m = fmaxf(m, row[c]);
            sc[t] = 1.0f / (1.0f + expf(-m));   // sigmoid(max) == max(sigmoid), monotone
        }
        __syncthreads();
        if (t < NQ) {
            float s = sc[t];
            int rank = 0;
            for (int j = 0; j < NQ; ++j) {
                float sj = sc[j];
                rank += ((sj > s) || (sj == s && j < t)) ? 1 : 0;   // stable descending
            }
            g_perm[ND + rank] = ND + t;
            out2[ND + rank] = (float)(ND + t);
        }
        if (t < ND) {
            g_perm[t] = t;
            out2[t] = (float)t;
            for (int h = 0; h < NH; ++h) g_afull[t * NH + h] = 0.f;
        }
    } else {
        // c0[h] = attn_b[h] + attn_W[h,:] @ post_b   (one wave per head)
        int h = t >> 6, lane = t & 63;
        float v = 0.f;
#pragma unroll
        for (int k = 0; k < 4; ++k) {
            int c = lane + 64 * k;
            v = fmaf(attn_W[h * ED + c], post_b[c], v);
        }
        for (int off = 32; off > 0; off >>= 1) v += __shfl_down(v, off, 64);
        if (lane == 0) g_c0[h] = attn_b[h] + v;
    }
}

// ---------------- K2: block (h=bid>>3, dc=bid&7): reduce fold partials for its 32-d slice,
//                     scatter WK, compute partial u & b2a over those 32 d's
__global__ __launch_bounds__(256) void precomp_u(const float* __restrict__ pre_W,
                                                 const float* __restrict__ pre_b) {
    int bid = blockIdx.x;
    int h = bid >> 3, dc = bid & 7;
    int t = threadIdx.x;
    __shared__ float sw[32];          // w2a[h, dc*32 .. +32]
    if (t < 32) {
        int d = dc * 32 + t;
        float s = 0.f;
#pragma unroll
        for (int cc = 0; cc < 8; ++cc) s += g_part[(size_t)(h * 8 + cc) * 512 + 256 + d];
        sw[t] = s;
    } else if (t < 64) {
        int dl = t - 32;
        int d = dc * 32 + dl;
        float s = 0.f;
#pragma unroll
        for (int cc = 0; cc < 8; ++cc) s += g_part[(size_t)(h * 8 + cc) * 512 + d];
        // d = f*64 + 2k + r  ->  WK[(k*4+f)*16 + h*2 + r]
        int f = d >> 6, rem = d & 63, k = rem >> 1, r = rem & 1;
        g_WK[(k * 4 + f) * 16 + h * 2 + r] = s;
    }
    __syncthreads();
    if (t == 0) {
        float b = 0.f;
        for (int dl = 0; dl < 32; ++dl) b = fmaf(sw[dl], pre_b[dc * 32 + dl], b);
        g_pb2a[h * 8 + dc] = b;
    }
    // partial u: pu[(h*8+dc)*256 + c] = sum_dl sw[dl] * pre_W[(dc*32+dl)*256 + c]
    float acc = 0.f;
    const float* pw = pre_W + (size_t)(dc * 32) * ED + t;
#pragma unroll
    for (int dl = 0; dl < 32; ++dl) acc = fmaf(sw[dl], pw[(size_t)dl * ED], acc);
    g_pu[(size_t)(h * 8 + dc) * ED + t] = acc;
}

// ---------------- K3: reduce u/b2a partials, then afull[64+q,h] = b2a[h] + remb[q,:] @ u[h,:]
#define PAD 260
__global__ __launch_bounds__(256) void precomp_afull(const float* __restrict__ rank_emb) {
    __shared__ float sU[NH][PAD];
    __shared__ float sR[32][PAD];
    __shared__ float sb2a[NH];
    int t = threadIdx.x;
    int q0 = blockIdx.x * 32;
    for (int v = t; v < NH * ED; v += 256) {
        int h = v >> 8, c = v & 255;
        float s = 0.f;
#pragma unroll
        for (int dc = 0; dc < 8; ++dc) s += g_pu[(size_t)(h * 8 + dc) * ED + c];
        sU[h][c] = s;
    }
    if (t < NH) {
        float s = 0.f;
#pragma unroll
        for (int dc = 0; dc < 8; ++dc) s += g_pb2a[t * 8 + dc];
        sb2a[t] = s;
    }
    for (int v = t; v < 32 * ED; v += 256)
        sR[v >> 8][v & 255] = rank_emb[(size_t)(q0 + (v >> 8)) * ED + (v & 255)];
    __syncthreads();
    int qloc = t >> 3, h = t & 7;
    float acc = sb2a[h];
    for (int c = 0; c < ED; ++c) acc = fmaf(sR[qloc][c], sU[h][c], acc);
    g_afull[(size_t)(ND + q0 + qloc) * NH + h] = acc;
}

// ---------------- K4: main per-pair kernel (f32 output), WK staged in LDS
__global__ __launch_bounds__(256) void relation_main(const float* __restrict__ boxes,
                                                     FreqArg fa,
                                                     float* __restrict__ out) {
    __shared__ float sWK[2048];
    int t = threadIdx.x;
    for (int v = t; v < 2048; v += 256) sWK[v] = g_WK[v];
    __syncthreads();

    int idx = blockIdx.x * 256 + t;
    int i = idx >> 9, j = idx & (NN - 1);
    int pi = i, pj = j;
    if (i >= ND && j >= ND) { pi = g_perm[i]; pj = g_perm[j]; }
    float4 b1 = ((const float4*)boxes)[pi];
    float4 b2 = ((const float4*)boxes)[pj];
    const float eps = 1e-5f;
    float feat[4];
    feat[0] = logf(fabsf(b1.x - b2.x) / (b1.z + eps) + 1.0f);
    feat[1] = logf(fabsf(b1.y - b2.y) / (b1.w + eps) + 1.0f);
    feat[2] = logf((b1.z + eps) / (b2.z + eps));
    feat[3] = logf((b1.w + eps) / (b2.w + eps));

    float acc[NH];
#pragma unroll
    for (int h = 0; h < NH; ++h) acc[h] = g_c0[h] + g_afull[i * NH + h] + g_afull[j * NH + h];

#pragma unroll 8
    for (int k = 0; k < 32; ++k) {
        float fr = fa.fr[k];
#pragma unroll
        for (int f = 0; f < 4; ++f) {
            float rev = feat[f] * fr;           // angle in revolutions
            rev = rev - floorf(rev);            // v_fract: safe domain for v_sin/v_cos
            float s = __builtin_amdgcn_sinf(rev);   // sin(2*pi*rev)
            float c = __builtin_amdgcn_cosf(rev);
            const float* w = sWK + ((k * 4 + f) << 4);   // uniform ds_read, broadcast
#pragma unroll
            for (int h = 0; h < NH; ++h) {
                acc[h] = fmaf(s, w[h * 2 + 0], acc[h]);
                acc[h] = fmaf(c, w[h * 2 + 1], acc[h]);
            }
        }
    }
#pragma unroll
    for (int h = 0; h < NH; ++h) {
        float v = acc[h] > 0.f ? acc[h] : 0.f;  // relu
        out[(size_t)h * (NN * NN) + idx] = v;
    }
}

extern "C" void kernel_launch(void* const* d_in, const int* in_sizes, int n_in,
                              void* d_out, int out_size, void* d_ws, size_t ws_size,
                              hipStream_t stream) {
    const float* boxes    = (const float*)d_in[0];
    const float* logits   = (const float*)d_in[1];
    const float* rank_emb = (const float*)d_in[2];
    const float* pre_W    = (const float*)d_in[3];
    const float* pre_b    = (const float*)d_in[4];
    const float* post_W   = (const float*)d_in[5];
    const float* post_b   = (const float*)d_in[6];
    const float* attn_W   = (const float*)d_in[7];
    const float* attn_b   = (const float*)d_in[8];
    float* out = (float*)d_out;

    precomp_fold<<<66, 512, 0, stream>>>(logits, attn_W, attn_b, post_W, post_b,
                                         out + (size_t)NH * NN * NN);
    precomp_u<<<64, 256, 0, stream>>>(pre_W, pre_b);
    precomp_afull<<<NQ / 32, 256, 0, stream>>>(rank_emb);

    FreqArg fa;
    for (int k = 0; k < 32; ++k)
        fa.fr[k] = (float)(100.0 / (2.0 * M_PI) / pow(10000.0, (double)k / 32.0));

    relation_main<<<(NN * NN) / 256, 256, 0, stream>>>(boxes, fa, out);
}

// Round 8
// 66.240 us; speedup vs baseline: 1.0140x; 1.0014x over previous
//
#include <hip/hip_runtime.h>
#include <hip/hip_bf16.h>
#include <math.h>

// Sizes fixed by the reference
#define NN 512
#define NQ 448
#define ND 64          // num_denoising
#define NC 91
#define ED 256
#define NH 8

struct FreqArg { float fr[32]; };

// All scratch in device globals — no dependence on ws_size.
__device__ int   g_perm[NN];
__device__ float g_WK[2048];        // 32 k * 4 f * 8 h * {sin,cos}
__device__ float g_c0[NH];
__device__ float g_afull[NN * NH];
__device__ float g_part[64 * 512];  // fold partials: [(h*8+cc)*512 + d']
__device__ float g_pu[64 * ED];     // u partials:    [(h*8+dc)*256 + c]
__device__ float g_pb2a[64];        // b2a partials:  [h*8+dc]
__device__ float g_scores[NQ];      // raw max-logit per query (sigmoid is monotone -> same order)

// ---------------- K1: blocks 0..63 = partial fold (h=bid>>3, cc=bid&7, 32 c's);
//                     blocks 64..71 = scores (1 wave per query, coalesced + shfl-reduce);
//                     block 72 = c0 (wave-reduce per head)
__global__ __launch_bounds__(512) void precomp_fold(const float* __restrict__ logits,
                                                    const float* __restrict__ attn_W,
                                                    const float* __restrict__ attn_b,
                                                    const float* __restrict__ post_W,
                                                    const float* __restrict__ post_b) {
    int bid = blockIdx.x;
    int t = threadIdx.x;
    if (bid < 64) {
        int h = bid >> 3, cc = bid & 7;
        __shared__ float sAW[32];
        if (t < 32) sAW[t] = attn_W[h * ED + cc * 32 + t];
        __syncthreads();
        float m = 0.f;
        const float* pw = post_W + (size_t)(cc * 32) * 512 + t;
#pragma unroll
        for (int ci = 0; ci < 32; ++ci) m = fmaf(sAW[ci], pw[(size_t)ci * 512], m);
        g_part[(size_t)bid * 512 + t] = m;
    } else if (bid < 72) {
        // one wave per query: coalesced row read + shuffle max-reduce
        int W = (bid - 64) * 8 + (t >> 6);   // wave id 0..63
        int lane = t & 63;
        for (int qi = 0; qi < 7; ++qi) {
            int q = W * 7 + qi;              // 0..447
            const float* row = logits + (size_t)(ND + q) * NC;
            float m = (lane < NC) ? row[lane] : -INFINITY;
            int c2 = lane + 64;
            if (c2 < NC) m = fmaxf(m, row[c2]);
            for (int off = 32; off > 0; off >>= 1) m = fmaxf(m, __shfl_down(m, off, 64));
            if (lane == 0) g_scores[q] = m;
        }
    } else {
        // c0[h] = attn_b[h] + attn_W[h,:] @ post_b   (one wave per head)
        int h = t >> 6, lane = t & 63;
        float v = 0.f;
#pragma unroll
        for (int k = 0; k < 4; ++k) {
            int c = lane + 64 * k;
            v = fmaf(attn_W[h * ED + c], post_b[c], v);
        }
        for (int off = 32; off > 0; off >>= 1) v += __shfl_down(v, off, 64);
        if (lane == 0) g_c0[h] = attn_b[h] + v;
    }
}

// ---------------- K2: blocks 0..63 = reduce fold partials (h=bid>>3, dc=bid&7), WK scatter,
//                     partial u & b2a; block 64 = stable descending argsort from g_scores
__global__ __launch_bounds__(256) void precomp_u(const float* __restrict__ pre_W,
                                                 const float* __restrict__ pre_b,
                                                 float* __restrict__ out2) {
    int bid = blockIdx.x;
    int t = threadIdx.x;
    if (bid < 64) {
        int h = bid >> 3, dc = bid & 7;
        __shared__ float sw[32];          // w2a[h, dc*32 .. +32]
        if (t < 32) {
            int d = dc * 32 + t;
            float s = 0.f;
#pragma unroll
            for (int cc = 0; cc < 8; ++cc) s += g_part[(size_t)(h * 8 + cc) * 512 + 256 + d];
            sw[t] = s;
        } else if (t < 64) {
            int dl = t - 32;
            int d = dc * 32 + dl;
            float s = 0.f;
#pragma unroll
            for (int cc = 0; cc < 8; ++cc) s += g_part[(size_t)(h * 8 + cc) * 512 + d];
            // d = f*64 + 2k + r  ->  WK[(k*4+f)*16 + h*2 + r]
            int f = d >> 6, rem = d & 63, k = rem >> 1, r = rem & 1;
            g_WK[(k * 4 + f) * 16 + h * 2 + r] = s;
        }
        __syncthreads();
        if (t == 0) {
            float b = 0.f;
            for (int dl = 0; dl < 32; ++dl) b = fmaf(sw[dl], pre_b[dc * 32 + dl], b);
            g_pb2a[h * 8 + dc] = b;
        }
        // partial u: pu[(h*8+dc)*256 + c] = sum_dl sw[dl] * pre_W[(dc*32+dl)*256 + c]
        float acc = 0.f;
        const float* pw = pre_W + (size_t)(dc * 32) * ED + t;
#pragma unroll
        for (int dl = 0; dl < 32; ++dl) acc = fmaf(sw[dl], pw[(size_t)dl * ED], acc);
        g_pu[(size_t)(h * 8 + dc) * ED + t] = acc;
    } else {
        // stable descending argsort by rank-count; each thread ranks 2 queries in one pass
        __shared__ float sc[NQ];
        for (int v = t; v < NQ; v += 256) sc[v] = g_scores[v];
        __syncthreads();
        int q1 = t, q2 = t + 256;
        float s1 = sc[q1];
        float s2 = (q2 < NQ) ? sc[q2] : 0.f;
        int r1 = 0, r2 = 0;
        for (int j = 0; j < NQ; ++j) {
            float sj = sc[j];
            r1 += ((sj > s1) || (sj == s1 && j < q1)) ? 1 : 0;
            r2 += ((sj > s2) || (sj == s2 && j < q2)) ? 1 : 0;
        }
        g_perm[ND + r1] = ND + q1;
        out2[ND + r1] = (float)(ND + q1);
        if (q2 < NQ) {
            g_perm[ND + r2] = ND + q2;
            out2[ND + r2] = (float)(ND + q2);
        }
        if (t < ND) {
            g_perm[t] = t;
            out2[t] = (float)t;
            for (int h = 0; h < NH; ++h) g_afull[t * NH + h] = 0.f;
        }
    }
}

// ---------------- K3: reduce u/b2a partials, then afull[64+q,h] = b2a[h] + remb[q,:] @ u[h,:]
#define PAD 260
__global__ __launch_bounds__(256) void precomp_afull(const float* __restrict__ rank_emb) {
    __shared__ float sU[NH][PAD];
    __shared__ float sR[32][PAD];
    __shared__ float sb2a[NH];
    int t = threadIdx.x;
    int q0 = blockIdx.x * 32;
    for (int v = t; v < NH * ED; v += 256) {
        int h = v >> 8, c = v & 255;
        float s = 0.f;
#pragma unroll
        for (int dc = 0; dc < 8; ++dc) s += g_pu[(size_t)(h * 8 + dc) * ED + c];
        sU[h][c] = s;
    }
    if (t < NH) {
        float s = 0.f;
#pragma unroll
        for (int dc = 0; dc < 8; ++dc) s += g_pb2a[t * 8 + dc];
        sb2a[t] = s;
    }
    for (int v = t; v < 32 * ED; v += 256)
        sR[v >> 8][v & 255] = rank_emb[(size_t)(q0 + (v >> 8)) * ED + (v & 255)];
    __syncthreads();
    int qloc = t >> 3, h = t & 7;
    float acc = sb2a[h];
    for (int c = 0; c < ED; ++c) acc = fmaf(sR[qloc][c], sU[h][c], acc);
    g_afull[(size_t)(ND + q0 + qloc) * NH + h] = acc;
}

// ---------------- K4: main per-pair kernel (f32 output), WK staged in LDS
__global__ __launch_bounds__(256) void relation_main(const float* __restrict__ boxes,
                                                     FreqArg fa,
                                                     float* __restrict__ out) {
    __shared__ float sWK[2048];
    int t = threadIdx.x;
    for (int v = t; v < 2048; v += 256) sWK[v] = g_WK[v];
    __syncthreads();

    int idx = blockIdx.x * 256 + t;
    int i = idx >> 9, j = idx & (NN - 1);
    int pi = i, pj = j;
    if (i >= ND && j >= ND) { pi = g_perm[i]; pj = g_perm[j]; }
    float4 b1 = ((const float4*)boxes)[pi];
    float4 b2 = ((const float4*)boxes)[pj];
    const float eps = 1e-5f;
    float feat[4];
    feat[0] = logf(fabsf(b1.x - b2.x) / (b1.z + eps) + 1.0f);
    feat[1] = logf(fabsf(b1.y - b2.y) / (b1.w + eps) + 1.0f);
    feat[2] = logf((b1.z + eps) / (b2.z + eps));
    feat[3] = logf((b1.w + eps) / (b2.w + eps));

    float acc[NH];
#pragma unroll
    for (int h = 0; h < NH; ++h) acc[h] = g_c0[h] + g_afull[i * NH + h] + g_afull[j * NH + h];

#pragma unroll 8
    for (int k = 0; k < 32; ++k) {
        float fr = fa.fr[k];
#pragma unroll
        for (int f = 0; f < 4; ++f) {
            float rev = feat[f] * fr;           // angle in revolutions
            rev = rev - floorf(rev);            // v_fract: safe domain for v_sin/v_cos
            float s = __builtin_amdgcn_sinf(rev);   // sin(2*pi*rev)
            float c = __builtin_amdgcn_cosf(rev);
            const float* w = sWK + ((k * 4 + f) << 4);   // uniform ds_read, broadcast
#pragma unroll
            for (int h = 0; h < NH; ++h) {
                acc[h] = fmaf(s, w[h * 2 + 0], acc[h]);
                acc[h] = fmaf(c, w[h * 2 + 1], acc[h]);
            }
        }
    }
#pragma unroll
    for (int h = 0; h < NH; ++h) {
        float v = acc[h] > 0.f ? acc[h] : 0.f;  // relu
        out[(size_t)h * (NN * NN) + idx] = v;
    }
}

extern "C" void kernel_launch(void* const* d_in, const int* in_sizes, int n_in,
                              void* d_out, int out_size, void* d_ws, size_t ws_size,
                              hipStream_t stream) {
    const float* boxes    = (const float*)d_in[0];
    const float* logits   = (const float*)d_in[1];
    const float* rank_emb = (const float*)d_in[2];
    const float* pre_W    = (const float*)d_in[3];
    const float* pre_b    = (const float*)d_in[4];
    const float* post_W   = (const float*)d_in[5];
    const float* post_b   = (const float*)d_in[6];
    const float* attn_W   = (const float*)d_in[7];
    const float* attn_b   = (const float*)d_in[8];
    float* out = (float*)d_out;

    precomp_fold<<<73, 512, 0, stream>>>(logits, attn_W, attn_b, post_W, post_b);
    precomp_u<<<65, 256, 0, stream>>>(pre_W, pre_b, out + (size_t)NH * NN * NN);
    precomp_afull<<<NQ / 32, 256, 0, stream>>>(rank_emb);

    FreqArg fa;
    for (int k = 0; k < 32; ++k)
        fa.fr[k] = (float)(100.0 / (2.0 * M_PI) / pow(10000.0, (double)k / 32.0));

    relation_main<<<(NN * NN) / 256, 256, 0, stream>>>(boxes, fa, out);
}

// Round 9
// 50.430 us; speedup vs baseline: 1.3319x; 1.3135x over previous
//
#include <hip/hip_runtime.h>
#include <hip/hip_bf16.h>
#include <math.h>

// Sizes fixed by the reference
#define NN 512
#define NQ 448
#define ND 64          // num_denoising
#define NC 91
#define ED 256
#define NH 8

typedef __attribute__((ext_vector_type(8))) short bf16x8;
typedef __attribute__((ext_vector_type(4))) float f32x4;

struct FreqArg { float fr[32]; };

// All scratch in device globals — no dependence on ws_size.
__device__ int   g_perm[NN];
__device__ float g_WK[2048];        // 32 k * 4 f * 8 h * {sin,cos}
__device__ float g_c0[NH];
__device__ float g_afull[NN * NH];
__device__ float g_part[64 * 512];  // fold partials: [(h*8+cc)*512 + d']
__device__ float g_pu[64 * ED];     // u partials:    [(h*8+dc)*256 + c]
__device__ float g_pb2a[64];        // b2a partials:  [h*8+dc]
__device__ float g_scores[NQ];      // raw max-logit (sigmoid monotone -> same order)
__device__ __align__(16) unsigned short g_WB[8 * 64 * 8];  // bf16 A-frags [step][lane][elem]

__device__ inline unsigned short f2bfbits(float x) {
    __hip_bfloat16 h = __float2bfloat16(x);
    union { __hip_bfloat16 b; unsigned short u; } cv; cv.b = h; return cv.u;
}

// ---------------- K1: blocks 0..63 = partial fold (h=bid>>3, cc=bid&7, 32 c's);
//                     blocks 64..71 = scores (1 wave/query, coalesced + shfl-reduce);
//                     block 72 = c0 (wave-reduce per head)
__global__ __launch_bounds__(512) void precomp_fold(const float* __restrict__ logits,
                                                    const float* __restrict__ attn_W,
                                                    const float* __restrict__ attn_b,
                                                    const float* __restrict__ post_W,
                                                    const float* __restrict__ post_b) {
    int bid = blockIdx.x;
    int t = threadIdx.x;
    if (bid < 64) {
        int h = bid >> 3, cc = bid & 7;
        __shared__ float sAW[32];
        if (t < 32) sAW[t] = attn_W[h * ED + cc * 32 + t];
        __syncthreads();
        float m = 0.f;
        const float* pw = post_W + (size_t)(cc * 32) * 512 + t;
#pragma unroll
        for (int ci = 0; ci < 32; ++ci) m = fmaf(sAW[ci], pw[(size_t)ci * 512], m);
        g_part[(size_t)bid * 512 + t] = m;
    } else if (bid < 72) {
        int W = (bid - 64) * 8 + (t >> 6);   // wave id 0..63
        int lane = t & 63;
        for (int qi = 0; qi < 7; ++qi) {
            int q = W * 7 + qi;              // 0..447
            const float* row = logits + (size_t)(ND + q) * NC;
            float m = (lane < NC) ? row[lane] : -INFINITY;
            int c2 = lane + 64;
            if (c2 < NC) m = fmaxf(m, row[c2]);
            for (int off = 32; off > 0; off >>= 1) m = fmaxf(m, __shfl_down(m, off, 64));
            if (lane == 0) g_scores[q] = m;
        }
    } else {
        int h = t >> 6, lane = t & 63;
        float v = 0.f;
#pragma unroll
        for (int k = 0; k < 4; ++k) {
            int c = lane + 64 * k;
            v = fmaf(attn_W[h * ED + c], post_b[c], v);
        }
        for (int off = 32; off > 0; off >>= 1) v += __shfl_down(v, off, 64);
        if (lane == 0) g_c0[h] = attn_b[h] + v;
    }
}

// ---------------- K2: blocks 0..63 = reduce fold partials (h=bid>>3, dc=bid&7), WK scatter,
//                     partial u & b2a; block 64 = stable descending argsort from g_scores
__global__ __launch_bounds__(256) void precomp_u(const float* __restrict__ pre_W,
                                                 const float* __restrict__ pre_b,
                                                 float* __restrict__ out2) {
    int bid = blockIdx.x;
    int t = threadIdx.x;
    if (bid < 64) {
        int h = bid >> 3, dc = bid & 7;
        __shared__ float sw[32];          // w2a[h, dc*32 .. +32]
        if (t < 32) {
            int d = dc * 32 + t;
            float s = 0.f;
#pragma unroll
            for (int cc = 0; cc < 8; ++cc) s += g_part[(size_t)(h * 8 + cc) * 512 + 256 + d];
            sw[t] = s;
        } else if (t < 64) {
            int dl = t - 32;
            int d = dc * 32 + dl;
            float s = 0.f;
#pragma unroll
            for (int cc = 0; cc < 8; ++cc) s += g_part[(size_t)(h * 8 + cc) * 512 + d];
            // d = f*64 + 2k + r  ->  WK[(k*4+f)*16 + h*2 + r]
            int f = d >> 6, rem = d & 63, k = rem >> 1, r = rem & 1;
            g_WK[(k * 4 + f) * 16 + h * 2 + r] = s;
        }
        __syncthreads();
        if (t == 0) {
            float b = 0.f;
            for (int dl = 0; dl < 32; ++dl) b = fmaf(sw[dl], pre_b[dc * 32 + dl], b);
            g_pb2a[h * 8 + dc] = b;
        }
        float acc = 0.f;
        const float* pw = pre_W + (size_t)(dc * 32) * ED + t;
#pragma unroll
        for (int dl = 0; dl < 32; ++dl) acc = fmaf(sw[dl], pw[(size_t)dl * ED], acc);
        g_pu[(size_t)(h * 8 + dc) * ED + t] = acc;
    } else {
        __shared__ float sc[NQ];
        for (int v = t; v < NQ; v += 256) sc[v] = g_scores[v];
        __syncthreads();
        int q1 = t, q2 = t + 256;
        float s1 = sc[q1];
        float s2 = (q2 < NQ) ? sc[q2] : 0.f;
        int r1 = 0, r2 = 0;
        for (int j = 0; j < NQ; ++j) {
            float sj = sc[j];
            r1 += ((sj > s1) || (sj == s1 && j < q1)) ? 1 : 0;
            r2 += ((sj > s2) || (sj == s2 && j < q2)) ? 1 : 0;
        }
        g_perm[ND + r1] = ND + q1;
        out2[ND + r1] = (float)(ND + q1);
        if (q2 < NQ) {
            g_perm[ND + r2] = ND + q2;
            out2[ND + r2] = (float)(ND + q2);
        }
        if (t < ND) {
            g_perm[t] = t;
            out2[t] = (float)t;
            for (int h = 0; h < NH; ++h) g_afull[t * NH + h] = 0.f;
        }
    }
}

// ---------------- K3: blocks 0..13 = reduce u/b2a partials + afull; block 14 = pack WB (bf16 A-frags)
#define PAD 260
__global__ __launch_bounds__(256) void precomp_afull(const float* __restrict__ rank_emb) {
    int t = threadIdx.x;
    if (blockIdx.x == 14) {
        // WB[step][lane][ii] = bf16(WK[k= s*4+(ii>>1), f= lane>>4, r= ii&1, h= lane&15]), 0 if h>=8
        for (int v = t; v < 4096; v += 256) {
            int s = v >> 9;
            int lane = (v >> 3) & 63;
            int ii = v & 7;
            int g = lane >> 4, hh = lane & 15;
            int k = s * 4 + (ii >> 1), r = ii & 1;
            float w = (hh < NH) ? g_WK[((k * 4 + g) << 4) + hh * 2 + r] : 0.f;
            g_WB[v] = f2bfbits(w);
        }
        return;
    }
    __shared__ float sU[NH][PAD];
    __shared__ float sR[32][PAD];
    __shared__ float sb2a[NH];
    int q0 = blockIdx.x * 32;
    for (int v = t; v < NH * ED; v += 256) {
        int h = v >> 8, c = v & 255;
        float s = 0.f;
#pragma unroll
        for (int dc = 0; dc < 8; ++dc) s += g_pu[(size_t)(h * 8 + dc) * ED + c];
        sU[h][c] = s;
    }
    if (t < NH) {
        float s = 0.f;
#pragma unroll
        for (int dc = 0; dc < 8; ++dc) s += g_pb2a[t * 8 + dc];
        sb2a[t] = s;
    }
    for (int v = t; v < 32 * ED; v += 256)
        sR[v >> 8][v & 255] = rank_emb[(size_t)(q0 + (v >> 8)) * ED + (v & 255)];
    __syncthreads();
    int qloc = t >> 3, h = t & 7;
    float acc = sb2a[h];
    for (int c = 0; c < ED; ++c) acc = fmaf(sR[qloc][c], sU[h][c], acc);
    g_afull[(size_t)(ND + q0 + qloc) * NH + h] = acc;
}

// ---------------- K4: MFMA main kernel. Wave = 16 pairs; A = weights (rows = heads),
//                     B = in-register sine features (cols = pairs); 8 x K=32 steps.
__global__ __launch_bounds__(256) void relation_main(const float* __restrict__ boxes,
                                                     FreqArg fa,
                                                     float* __restrict__ out) {
    __shared__ bf16x8 sWB[8][64];
    int t = threadIdx.x;
    ((uint4*)sWB)[t]       = ((const uint4*)g_WB)[t];
    ((uint4*)sWB)[t + 256] = ((const uint4*)g_WB)[t + 256];
    __syncthreads();

    int wave = t >> 6, lane = t & 63;
    int g = lane >> 4, r = lane & 15;
    int i = blockIdx.x >> 3;
    int j = ((blockIdx.x & 7) << 6) + (wave << 4) + r;

    int pi = i, pj = j;
    if (i >= ND) { pi = g_perm[i]; if (j >= ND) pj = g_perm[j]; }
    float4 b1 = ((const float4*)boxes)[pi];
    float4 b2 = ((const float4*)boxes)[pj];
    const float eps = 1e-5f;
    // this lane only needs feat[g] of its pair (i, j)
    float ft;
    if (g == 0)      ft = logf(fabsf(b1.x - b2.x) / (b1.z + eps) + 1.0f);
    else if (g == 1) ft = logf(fabsf(b1.y - b2.y) / (b1.w + eps) + 1.0f);
    else if (g == 2) ft = logf((b1.z + eps) / (b2.z + eps));
    else             ft = logf((b1.w + eps) / (b2.w + eps));

    f32x4 acc = {0.f, 0.f, 0.f, 0.f};
#pragma unroll
    for (int s = 0; s < 8; ++s) {
        bf16x8 bfrag;
#pragma unroll
        for (int a = 0; a < 4; ++a) {
            float rev = ft * fa.fr[s * 4 + a];
            rev -= floorf(rev);
            float sv = __builtin_amdgcn_sinf(rev);   // sin(2*pi*rev)
            float cv = __builtin_amdgcn_cosf(rev);
            bfrag[2 * a]     = (short)f2bfbits(sv);
            bfrag[2 * a + 1] = (short)f2bfbits(cv);
        }
        acc = __builtin_amdgcn_mfma_f32_16x16x32_bf16(sWB[s][lane], bfrag, acc, 0, 0, 0);
    }

    // D: row = g*4 + q (head, valid < 8 -> g < 2), col = r (pair)
    if (g < 2) {
        float4 cb = *(const float4*)(g_c0 + g * 4);
        float4 ai = *(const float4*)(g_afull + i * NH + g * 4);
        float4 aj = *(const float4*)(g_afull + j * NH + g * 4);
        const float* cbp = (const float*)&cb;
        const float* aip = (const float*)&ai;
        const float* ajp = (const float*)&aj;
#pragma unroll
        for (int q = 0; q < 4; ++q) {
            int h = g * 4 + q;
            float v = acc[q] + cbp[q] + aip[q] + ajp[q];
            v = v > 0.f ? v : 0.f;
            out[(size_t)h * (NN * NN) + i * NN + j] = v;
        }
    }
}

extern "C" void kernel_launch(void* const* d_in, const int* in_sizes, int n_in,
                              void* d_out, int out_size, void* d_ws, size_t ws_size,
                              hipStream_t stream) {
    const float* boxes    = (const float*)d_in[0];
    const float* logits   = (const float*)d_in[1];
    const float* rank_emb = (const float*)d_in[2];
    const float* pre_W    = (const float*)d_in[3];
    const float* pre_b    = (const float*)d_in[4];
    const float* post_W   = (const float*)d_in[5];
    const float* post_b   = (const float*)d_in[6];
    const float* attn_W   = (const float*)d_in[7];
    const float* attn_b   = (const float*)d_in[8];
    float* out = (float*)d_out;

    precomp_fold<<<73, 512, 0, stream>>>(logits, attn_W, attn_b, post_W, post_b);
    precomp_u<<<65, 256, 0, stream>>>(pre_W, pre_b, out + (size_t)NH * NN * NN);
    precomp_afull<<<15, 256, 0, stream>>>(rank_emb);

    FreqArg fa;
    for (int k = 0; k < 32; ++k)
        fa.fr[k] = (float)(100.0 / (2.0 * M_PI) / pow(10000.0, (double)k / 32.0));

    relation_main<<<4096, 256, 0, stream>>>(boxes, fa, out);
}

// Round 10
// 45.018 us; speedup vs baseline: 1.4920x; 1.1202x over previous
//
#include <hip/hip_runtime.h>
#include <hip/hip_bf16.h>
#include <math.h>

// Sizes fixed by the reference
#define NN 512
#define NQ 448
#define ND 64          // num_denoising
#define NC 91
#define ED 256
#define NH 8

typedef __attribute__((ext_vector_type(8))) short bf16x8;
typedef __attribute__((ext_vector_type(4))) float f32x4;

struct FreqArg { float fr[32]; };

// Device-global scratch
__device__ int   g_perm[NN];
__device__ float g_c0[NH];
__device__ float g_afull[NN * NH];
__device__ float g_part[64 * 512];  // fold partials: [(h*8+cc)*512 + d']  (d'<256: pos, >=256: rank)
__device__ float g_scores[NQ];      // raw max-logit (sigmoid monotone -> same order)
__device__ float g_nr[NQ * ED];     // normal_rank = rank_emb @ pre_W^T + pre_b
__device__ __align__(16) unsigned short g_WB[8 * 64 * 8];  // bf16 A-frags [step][lane][elem]

__device__ inline unsigned short f2bfbits(float x) {
    __hip_bfloat16 h = __float2bfloat16(x);
    union { __hip_bfloat16 b; unsigned short u; } cv; cv.b = h; return cv.u;
}

// ---------------- K1: 0..63 fold partials; 64..71 scores; 72 c0; 73..296 nr tiles (16q x 32d)
__global__ __launch_bounds__(512) void precomp1(const float* __restrict__ logits,
                                                const float* __restrict__ attn_W,
                                                const float* __restrict__ attn_b,
                                                const float* __restrict__ post_W,
                                                const float* __restrict__ post_b,
                                                const float* __restrict__ pre_W,
                                                const float* __restrict__ pre_b,
                                                const float* __restrict__ rank_emb) {
    __shared__ float smem[48 * 257];     // nr: sP[32][257] + sR[16][257]; fold: first 32 floats
    int bid = blockIdx.x;
    int t = threadIdx.x;
    if (bid < 64) {
        int h = bid >> 3, cc = bid & 7;
        float* sAW = smem;
        if (t < 32) sAW[t] = attn_W[h * ED + cc * 32 + t];
        __syncthreads();
        float m = 0.f;
        const float* pw = post_W + (size_t)(cc * 32) * 512 + t;
#pragma unroll
        for (int ci = 0; ci < 32; ++ci) m = fmaf(sAW[ci], pw[(size_t)ci * 512], m);
        g_part[(size_t)bid * 512 + t] = m;
    } else if (bid < 72) {
        int W = (bid - 64) * 8 + (t >> 6);   // wave id 0..63
        int lane = t & 63;
        for (int qi = 0; qi < 7; ++qi) {
            int q = W * 7 + qi;              // 0..447
            const float* row = logits + (size_t)(ND + q) * NC;
            float m = (lane < NC) ? row[lane] : -INFINITY;
            int c2 = lane + 64;
            if (c2 < NC) m = fmaxf(m, row[c2]);
            for (int off = 32; off > 0; off >>= 1) m = fmaxf(m, __shfl_down(m, off, 64));
            if (lane == 0) g_scores[q] = m;
        }
    } else if (bid == 72) {
        int h = t >> 6, lane = t & 63;
        float v = 0.f;
#pragma unroll
        for (int k = 0; k < 4; ++k) {
            int c = lane + 64 * k;
            v = fmaf(attn_W[h * ED + c], post_b[c], v);
        }
        for (int off = 32; off > 0; off >>= 1) v += __shfl_down(v, off, 64);
        if (lane == 0) g_c0[h] = attn_b[h] + v;
    } else {
        // nr tile: 16 q-rows x 32 d-rows, K=256 in LDS
        int nb = bid - 73;                   // 0..223 = 28 q-tiles x 8 d-tiles
        int q0 = (nb >> 3) * 16, d0 = (nb & 7) * 32;
        float* sP = smem;                    // [32][257] pre_W rows
        float* sR = smem + 32 * 257;         // [16][257] rank_emb rows
        for (int v = t; v < 32 * 256; v += 512)
            sP[(v >> 8) * 257 + (v & 255)] = pre_W[(size_t)(d0 + (v >> 8)) * ED + (v & 255)];
        for (int v = t; v < 16 * 256; v += 512)
            sR[(v >> 8) * 257 + (v & 255)] = rank_emb[(size_t)(q0 + (v >> 8)) * ED + (v & 255)];
        __syncthreads();
        int q = t >> 5, dl = t & 31;
        float acc = pre_b[d0 + dl];
#pragma unroll 8
        for (int e = 0; e < 256; ++e) acc = fmaf(sR[q * 257 + e], sP[dl * 257 + e], acc);
        g_nr[(size_t)(q0 + q) * ED + d0 + dl] = acc;
    }
}

// ---------------- K2: 0..55 afull tiles (8 q each); 56..57 WB pack; 58 argsort
__global__ __launch_bounds__(256) void precomp2(float* __restrict__ out2) {
    int bid = blockIdx.x;
    int t = threadIdx.x;
    if (bid < 56) {
        __shared__ float sW[NH * 260];   // w2a[h][d] (redundant per-block reduce)
        __shared__ float sN[NH * 260];   // nr rows for this q-tile
        int q0 = bid * 8;
        for (int v = t; v < 2048; v += 256) {
            int h = v >> 8, d = v & 255;
            float s = 0.f;
#pragma unroll
            for (int cc = 0; cc < 8; ++cc) s += g_part[(size_t)(h * 8 + cc) * 512 + 256 + d];
            sW[h * 260 + d] = s;
        }
        for (int v = t; v < 2048; v += 256)
            sN[(v >> 8) * 260 + (v & 255)] = g_nr[(size_t)(q0 + (v >> 8)) * ED + (v & 255)];
        __syncthreads();
        // 64 outputs (8q x 8h), 4 threads each over interleaved e = sub + 4*e2
        int o = t >> 2, sub = t & 3;
        int q = o >> 3, h = o & 7;
        float a = 0.f;
#pragma unroll 8
        for (int e2 = 0; e2 < 64; ++e2) {
            int e = sub + 4 * e2;
            a = fmaf(sN[q * 260 + e], sW[h * 260 + e], a);
        }
        a += __shfl_xor(a, 1, 64);
        a += __shfl_xor(a, 2, 64);
        if (sub == 0) g_afull[(size_t)(ND + q0 + q) * NH + h] = a;
    } else if (bid < 58) {
        // WB pack straight from fold partials
        for (int vv = t; vv < 2048; vv += 256) {
            int v = (bid - 56) * 2048 + vv;
            int s = v >> 9;
            int lane = (v >> 3) & 63;
            int ii = v & 7;
            int g = lane >> 4, hh = lane & 15;
            int k = s * 4 + (ii >> 1), r = ii & 1;
            int d = g * 64 + 2 * k + r;
            float w = 0.f;
            if (hh < NH) {
#pragma unroll
                for (int cc = 0; cc < 8; ++cc) w += g_part[(size_t)(hh * 8 + cc) * 512 + d];
            }
            g_WB[v] = f2bfbits(w);
        }
    } else {
        // stable descending argsort by rank-count from g_scores
        __shared__ float sc[NQ];
        for (int v = t; v < NQ; v += 256) sc[v] = g_scores[v];
        __syncthreads();
        int q1 = t, q2 = t + 256;
        float s1 = sc[q1];
        float s2 = (q2 < NQ) ? sc[q2] : 0.f;
        int r1 = 0, r2 = 0;
        for (int j = 0; j < NQ; ++j) {
            float sj = sc[j];
            r1 += ((sj > s1) || (sj == s1 && j < q1)) ? 1 : 0;
            r2 += ((sj > s2) || (sj == s2 && j < q2)) ? 1 : 0;
        }
        g_perm[ND + r1] = ND + q1;
        out2[ND + r1] = (float)(ND + q1);
        if (q2 < NQ) {
            g_perm[ND + r2] = ND + q2;
            out2[ND + r2] = (float)(ND + q2);
        }
        if (t < ND) {
            g_perm[t] = t;
            out2[t] = (float)t;
            for (int h = 0; h < NH; ++h) g_afull[t * NH + h] = 0.f;
        }
    }
}

// ---------------- K3: MFMA main kernel. Wave = 16 pairs; A = weights (rows = heads),
//                     B = in-register sine features (cols = pairs); 8 x K=32 steps.
__global__ __launch_bounds__(256) void relation_main(const float* __restrict__ boxes,
                                                     FreqArg fa,
                                                     float* __restrict__ out) {
    __shared__ bf16x8 sWB[8][64];
    int t = threadIdx.x;
    ((uint4*)sWB)[t]       = ((const uint4*)g_WB)[t];
    ((uint4*)sWB)[t + 256] = ((const uint4*)g_WB)[t + 256];
    __syncthreads();

    int wave = t >> 6, lane = t & 63;
    int g = lane >> 4, r = lane & 15;
    int i = blockIdx.x >> 3;
    int j = ((blockIdx.x & 7) << 6) + (wave << 4) + r;

    int pi = i, pj = j;
    if (i >= ND && j >= ND) { pi = g_perm[i]; pj = g_perm[j]; }   // permute ONLY the [64:,64:] block
    float4 b1 = ((const float4*)boxes)[pi];
    float4 b2 = ((const float4*)boxes)[pj];
    const float eps = 1e-5f;
    float ft;
    if (g == 0)      ft = logf(fabsf(b1.x - b2.x) / (b1.z + eps) + 1.0f);
    else if (g == 1) ft = logf(fabsf(b1.y - b2.y) / (b1.w + eps) + 1.0f);
    else if (g == 2) ft = logf((b1.z + eps) / (b2.z + eps));
    else             ft = logf((b1.w + eps) / (b2.w + eps));

    f32x4 acc = {0.f, 0.f, 0.f, 0.f};
#pragma unroll
    for (int s = 0; s < 8; ++s) {
        bf16x8 bfrag;
#pragma unroll
        for (int a = 0; a < 4; ++a) {
            float rev = ft * fa.fr[s * 4 + a];
            rev -= floorf(rev);
            float sv = __builtin_amdgcn_sinf(rev);   // sin(2*pi*rev)
            float cv = __builtin_amdgcn_cosf(rev);
            bfrag[2 * a]     = (short)f2bfbits(sv);
            bfrag[2 * a + 1] = (short)f2bfbits(cv);
        }
        acc = __builtin_amdgcn_mfma_f32_16x16x32_bf16(sWB[s][lane], bfrag, acc, 0, 0, 0);
    }

    // D: row = g*4 + q (head, valid < 8 -> g < 2), col = r (pair)
    if (g < 2) {
        float4 cb = *(const float4*)(g_c0 + g * 4);
        float4 ai = *(const float4*)(g_afull + i * NH + g * 4);
        float4 aj = *(const float4*)(g_afull + j * NH + g * 4);
        const float* cbp = (const float*)&cb;
        const float* aip = (const float*)&ai;
        const float* ajp = (const float*)&aj;
#pragma unroll
        for (int q = 0; q < 4; ++q) {
            int h = g * 4 + q;
            float v = acc[q] + cbp[q] + aip[q] + ajp[q];
            v = v > 0.f ? v : 0.f;
            out[(size_t)h * (NN * NN) + i * NN + j] = v;
        }
    }
}

extern "C" void kernel_launch(void* const* d_in, const int* in_sizes, int n_in,
                              void* d_out, int out_size, void* d_ws, size_t ws_size,
                              hipStream_t stream) {
    const float* boxes    = (const float*)d_in[0];
    const float* logits   = (const float*)d_in[1];
    const float* rank_emb = (const float*)d_in[2];
    const float* pre_W    = (const float*)d_in[3];
    const float* pre_b    = (const float*)d_in[4];
    const float* post_W   = (const float*)d_in[5];
    const float* post_b   = (const float*)d_in[6];
    const float* attn_W   = (const float*)d_in[7];
    const float* attn_b   = (const float*)d_in[8];
    float* out = (float*)d_out;

    precomp1<<<297, 512, 0, stream>>>(logits, attn_W, attn_b, post_W, post_b,
                                      pre_W, pre_b, rank_emb);
    precomp2<<<59, 256, 0, stream>>>(out + (size_t)NH * NN * NN);

    FreqArg fa;
    for (int k = 0; k < 32; ++k)
        fa.fr[k] = (float)(100.0 / (2.0 * M_PI) / pow(10000.0, (double)k / 32.0));

    relation_main<<<4096, 256, 0, stream>>>(boxes, fa, out);
}